// Round 1
// baseline (1746.555 us; speedup 1.0000x reference)
//
#include <hip/hip_runtime.h>

#define N_NODES 100000
#define N_EDGES 3200000

// ---------------- degree / norm ----------------

__global__ void k_deg_init(float* __restrict__ deg) {
    int i = blockIdx.x * blockDim.x + threadIdx.x;
    if (i < N_NODES) deg[i] = 1.0f;  // self-loop
}

__global__ void k_deg_acc(const int* __restrict__ dst, float* __restrict__ deg) {
    int e = blockIdx.x * blockDim.x + threadIdx.x;
    if (e < N_EDGES) atomicAdd(&deg[dst[e]], 1.0f);
}

__global__ void k_dinv(float* __restrict__ deg) {
    int i = blockIdx.x * blockDim.x + threadIdx.x;
    if (i < N_NODES) deg[i] = rsqrtf(deg[i]);  // deg >= 1 always
}

// ---------------- self-loop init (out = dinv^2 * feat [+ bias]) ----------------

__global__ void k_selfloop_init64(const float* __restrict__ feat,
                                  const float* __restrict__ dinv,
                                  const float* __restrict__ bias,
                                  float* __restrict__ out) {
    long long t = (long long)blockIdx.x * blockDim.x + threadIdx.x;
    if (t >= (long long)N_NODES * 64) return;
    int i = (int)(t >> 6);
    int f = (int)(t & 63);
    float d = dinv[i];
    float b = bias ? bias[f] : 0.0f;
    out[t] = d * d * feat[t] + b;
}

// ---------------- edge aggregation: out[dst] += dinv[s]*dinv[d]*feat[src], F=64 ----------------

__global__ void k_edge_agg64(const int* __restrict__ src, const int* __restrict__ dst,
                             const float* __restrict__ dinv,
                             const float* __restrict__ feat,
                             float* __restrict__ out) {
    long long t = (long long)blockIdx.x * blockDim.x + threadIdx.x;
    int e = (int)(t >> 6);
    int f = (int)(t & 63);
    if (e >= N_EDGES) return;
    int s = src[e];
    int d = dst[e];
    float norm = dinv[s] * dinv[d];
    atomicAdd(&out[(long long)d * 64 + f], norm * feat[(long long)s * 64 + f]);
}

// ---------------- GEMM1: H = relu(A(Nx64) @ W1(64x128) + b1) ----------------

__global__ void k_gemm1_relu(const float* __restrict__ A, const float* __restrict__ W,
                             const float* __restrict__ b, float* __restrict__ H) {
    __shared__ float s[64];
    int row = blockIdx.x;
    int j = threadIdx.x;  // 0..127
    if (j < 64) s[j] = A[(long long)row * 64 + j];
    __syncthreads();
    float acc = b[j];
#pragma unroll
    for (int k = 0; k < 64; ++k) acc += s[k] * W[k * 128 + j];
    H[(long long)row * 128 + j] = fmaxf(acc, 0.0f);
}

// ---------------- GEMM2: P = H(Nx128) @ W2(128x64), 4 rows per 256-thread block ----------------

__global__ void k_gemm2(const float* __restrict__ H, const float* __restrict__ W,
                        float* __restrict__ P) {
    __shared__ float s[4][128];
    int r0 = blockIdx.x * 4;
    for (int idx = threadIdx.x; idx < 4 * 128; idx += 256) {
        int rr = idx >> 7;
        int kk = idx & 127;
        int row = r0 + rr;
        s[rr][kk] = (row < N_NODES) ? H[(long long)row * 128 + kk] : 0.0f;
    }
    __syncthreads();
    int lr = threadIdx.x >> 6;  // 0..3
    int j = threadIdx.x & 63;
    int row = r0 + lr;
    if (row >= N_NODES) return;
    float acc = 0.0f;
#pragma unroll
    for (int k = 0; k < 128; ++k) acc += s[lr][k] * W[k * 64 + j];
    P[(long long)row * 64 + j] = acc;
}

// ---------------- launch ----------------

extern "C" void kernel_launch(void* const* d_in, const int* in_sizes, int n_in,
                              void* d_out, int out_size, void* d_ws, size_t ws_size,
                              hipStream_t stream) {
    const float* x  = (const float*)d_in[0];
    const int*   ei = (const int*)d_in[1];
    const float* W1 = (const float*)d_in[2];
    const float* b1 = (const float*)d_in[3];
    const float* W2 = (const float*)d_in[4];
    const float* b2 = (const float*)d_in[5];
    float* out = (float*)d_out;

    const int* srcE = ei;            // edge_index[0]
    const int* dstE = ei + N_EDGES;  // edge_index[1]

    float* ws   = (float*)d_ws;
    float* dinv = ws;                                  // N
    float* aggx = ws + N_NODES;                        // N*64 (reused as p2)
    float* h1   = aggx + (long long)N_NODES * 64;      // N*128
    float* p2   = aggx;                                // reuse: aggx dead after GEMM1

    const int B = 256;
    long long nodeF = (long long)N_NODES * 64;
    long long edgeF = (long long)N_EDGES * 64;

    // degrees -> dinv
    k_deg_init<<<(N_NODES + B - 1) / B, B, 0, stream>>>(dinv);
    k_deg_acc<<<(N_EDGES + B - 1) / B, B, 0, stream>>>(dstE, dinv);
    k_dinv<<<(N_NODES + B - 1) / B, B, 0, stream>>>(dinv);

    // layer 1: aggregate x (64-wide), then GEMM+bias+relu
    k_selfloop_init64<<<(int)((nodeF + B - 1) / B), B, 0, stream>>>(x, dinv, nullptr, aggx);
    k_edge_agg64<<<(int)((edgeF + B - 1) / B), B, 0, stream>>>(srcE, dstE, dinv, x, aggx);
    k_gemm1_relu<<<N_NODES, 128, 0, stream>>>(aggx, W1, b1, h1);

    // layer 2: GEMM first (64-wide), then aggregate into out
    k_gemm2<<<(N_NODES + 3) / 4, 256, 0, stream>>>(h1, W2, p2);
    k_selfloop_init64<<<(int)((nodeF + B - 1) / B), B, 0, stream>>>(p2, dinv, b2, out);
    k_edge_agg64<<<(int)((edgeF + B - 1) / B), B, 0, stream>>>(srcE, dstE, dinv, p2, out);
}

// Round 2
// 1084.258 us; speedup vs baseline: 1.6108x; 1.6108x over previous
//
#include <hip/hip_runtime.h>

#define N_NODES 100000
#define N_EDGES 3200000

// ---------------- CSR build ----------------

__global__ void k_hist_zero(int* __restrict__ hist) {
    int i = blockIdx.x * blockDim.x + threadIdx.x;
    if (i < N_NODES) hist[i] = 0;
}

__global__ void k_hist(const int* __restrict__ dst, int* __restrict__ hist) {
    int e = blockIdx.x * blockDim.x + threadIdx.x;
    if (e < N_EDGES) atomicAdd(&hist[dst[e]], 1);
}

// single block of 1024: exclusive scan of hist -> rowstart, rowstart[N]=E
__global__ void k_scan(const int* __restrict__ hist, int* __restrict__ rowstart) {
    __shared__ int part[1024];
    int tid = threadIdx.x;
    const int CH = (N_NODES + 1023) / 1024;  // 98
    int begI = tid * CH;
    int endI = begI + CH;
    if (endI > N_NODES) endI = N_NODES;
    int sum = 0;
    for (int i = begI; i < endI; ++i) sum += hist[i];
    part[tid] = sum;
    __syncthreads();
    for (int off = 1; off < 1024; off <<= 1) {
        int v = (tid >= off) ? part[tid - off] : 0;
        __syncthreads();
        part[tid] += v;
        __syncthreads();
    }
    int run = (tid == 0) ? 0 : part[tid - 1];
    for (int i = begI; i < endI; ++i) {
        rowstart[i] = run;
        run += hist[i];
    }
    if (tid == 1023) rowstart[N_NODES] = run;
}

// dinv = rsqrt(in_degree + 1 self-loop); cursor = rowstart copy
__global__ void k_dinv_cursor(const int* __restrict__ hist, const int* __restrict__ rowstart,
                              float* __restrict__ dinv, int* __restrict__ cursor) {
    int i = blockIdx.x * blockDim.x + threadIdx.x;
    if (i < N_NODES) {
        dinv[i] = rsqrtf((float)(hist[i] + 1));
        cursor[i] = rowstart[i];
    }
}

__global__ void k_scatter(const int* __restrict__ src, const int* __restrict__ dst,
                          int* __restrict__ cursor, int* __restrict__ csr_src) {
    int e = blockIdx.x * blockDim.x + threadIdx.x;
    if (e < N_EDGES) {
        int p = atomicAdd(&cursor[dst[e]], 1);
        csr_src[p] = src[e];
    }
}

// ---------------- feature scaling ----------------

// out[i][f] = dinv[i] * in[i][f]
__global__ void k_scale(const float* __restrict__ in, const float* __restrict__ dinv,
                        float* __restrict__ out) {
    long long t = (long long)blockIdx.x * blockDim.x + threadIdx.x;
    if (t >= (long long)N_NODES * 64) return;
    out[t] = dinv[(int)(t >> 6)] * in[t];
}

__global__ void k_scale_inplace(float* __restrict__ a, const float* __restrict__ dinv) {
    long long t = (long long)blockIdx.x * blockDim.x + threadIdx.x;
    if (t >= (long long)N_NODES * 64) return;
    a[t] *= dinv[(int)(t >> 6)];
}

// ---------------- gather aggregation ----------------
// out[d][f] = dinv[d] * (xs[d][f] + sum_{s in in(d)} xs[s][f]) + bias[f]
// one wave per node, lane = feature

__global__ __launch_bounds__(256) void k_gather(
    const int* __restrict__ rowstart, const int* __restrict__ csr_src,
    const float* __restrict__ dinv, const float* __restrict__ xs,
    const float* __restrict__ bias, float* __restrict__ out)
{
    int node = blockIdx.x * 4 + (threadIdx.x >> 6);
    if (node >= N_NODES) return;
    int lane = threadIdx.x & 63;
    int beg = rowstart[node];
    int deg = rowstart[node + 1] - beg;
    float acc0 = xs[(long long)node * 64 + lane];  // self loop (already dinv-scaled)
    float acc1 = 0.f;
    for (int base = 0; base < deg; base += 64) {
        int rem = deg - base;
        if (rem > 64) rem = 64;
        int mye = (lane < rem) ? csr_src[beg + base + lane] : 0;  // coalesced edge load
        int j = 0;
        for (; j + 1 < rem; j += 2) {
            int s0 = __shfl(mye, j);
            int s1 = __shfl(mye, j + 1);
            acc0 += xs[(long long)s0 * 64 + lane];
            acc1 += xs[(long long)s1 * 64 + lane];
        }
        if (j < rem) {
            int s0 = __shfl(mye, j);
            acc0 += xs[(long long)s0 * 64 + lane];
        }
    }
    float d = dinv[node];
    float b = bias ? bias[lane] : 0.f;
    out[(long long)node * 64 + lane] = d * (acc0 + acc1) + b;
}

// ---------------- fused GEMM: P = relu(A@W1 + b1) @ W2 ----------------
// A: [N,64], W1: [64,128], W2: [128,64], P: [N,64]

#define GROWS 8
__global__ __launch_bounds__(256) void k_fused_gemm(
    const float* __restrict__ A, const float* __restrict__ W1,
    const float* __restrict__ b1, const float* __restrict__ W2,
    float* __restrict__ P)
{
    __shared__ float sW1[64 * 128];   // 32KB
    __shared__ float sW2[128 * 64];   // 32KB
    __shared__ float sH[GROWS][128];
    __shared__ float sA[GROWS][64];
    int tid = threadIdx.x;
    for (int i = tid; i < 64 * 128; i += 256) sW1[i] = W1[i];
    for (int i = tid; i < 128 * 64; i += 256) sW2[i] = W2[i];
    int r0 = blockIdx.x * GROWS;
    for (int i = tid; i < GROWS * 64; i += 256) {
        int rr = i >> 6;
        int row = r0 + rr;
        sA[rr][i & 63] = (row < N_NODES) ? A[(long long)row * 64 + (i & 63)] : 0.f;
    }
    __syncthreads();
    // phase 1: H = relu(A@W1 + b1); 256 threads -> col j = tid&127, 4 rows each
    {
        int j = tid & 127;
        int rbase = (tid >> 7) * (GROWS / 2);  // 0 or 4
        float bb = b1[j];
        for (int rr = rbase; rr < rbase + GROWS / 2; ++rr) {
            float acc = bb;
#pragma unroll
            for (int k = 0; k < 64; ++k) acc += sA[rr][k] * sW1[k * 128 + j];
            sH[rr][j] = fmaxf(acc, 0.f);
        }
    }
    __syncthreads();
    // phase 2: P = H@W2; col j = tid&63, 2 rows each
    {
        int j = tid & 63;
        int rbase = (tid >> 6) * (GROWS / 4);  // 0,2,4,6
        for (int rr = rbase; rr < rbase + GROWS / 4; ++rr) {
            int row = r0 + rr;
            if (row >= N_NODES) continue;
            float acc = 0.f;
#pragma unroll
            for (int k = 0; k < 128; ++k) acc += sH[rr][k] * sW2[k * 64 + j];
            P[(long long)row * 64 + j] = acc;
        }
    }
}

// ---------------- launch ----------------

extern "C" void kernel_launch(void* const* d_in, const int* in_sizes, int n_in,
                              void* d_out, int out_size, void* d_ws, size_t ws_size,
                              hipStream_t stream) {
    const float* x  = (const float*)d_in[0];
    const int*   ei = (const int*)d_in[1];
    const float* W1 = (const float*)d_in[2];
    const float* b1 = (const float*)d_in[3];
    const float* W2 = (const float*)d_in[4];
    const float* b2 = (const float*)d_in[5];
    float* out = (float*)d_out;

    const int* srcE = ei;            // edge_index[0]
    const int* dstE = ei + N_EDGES;  // edge_index[1]

    // workspace layout
    char* w = (char*)d_ws;
    int*   hist     = (int*)w;                          w += sizeof(int) * N_NODES;
    int*   rowstart = (int*)w;                          w += sizeof(int) * (N_NODES + 1);
    int*   cursor   = (int*)w;                          w += sizeof(int) * N_NODES;
    int*   csr_src  = (int*)w;                          w += sizeof(int) * N_EDGES;
    float* dinv     = (float*)w;                        w += sizeof(float) * N_NODES;
    float* xs       = (float*)w;                        w += sizeof(float) * (size_t)N_NODES * 64;
    float* agg1     = (float*)w;                        w += sizeof(float) * (size_t)N_NODES * 64;
    float* p2 = xs;  // xs dead after layer-1 gather

    const int B = 256;
    int gN  = (N_NODES + B - 1) / B;
    int gE  = (N_EDGES + B - 1) / B;
    int gNF = (int)(((long long)N_NODES * 64 + B - 1) / B);

    // CSR build + dinv
    k_hist_zero<<<gN, B, 0, stream>>>(hist);
    k_hist<<<gE, B, 0, stream>>>(dstE, hist);
    k_scan<<<1, 1024, 0, stream>>>(hist, rowstart);
    k_dinv_cursor<<<gN, B, 0, stream>>>(hist, rowstart, dinv, cursor);
    k_scatter<<<gE, B, 0, stream>>>(srcE, dstE, cursor, csr_src);

    // layer 1: xs = dinv*x; agg1 = dinv*(xs self + gathered); then fused GEMMs
    k_scale<<<gNF, B, 0, stream>>>(x, dinv, xs);
    k_gather<<<(N_NODES + 3) / 4, 256, 0, stream>>>(rowstart, csr_src, dinv, xs, nullptr, agg1);
    k_fused_gemm<<<(N_NODES + GROWS - 1) / GROWS, 256, 0, stream>>>(agg1, W1, b1, W2, p2);

    // layer 2: scale p2 in place, gather into out (+b2)
    k_scale_inplace<<<gNF, B, 0, stream>>>(p2, dinv);
    k_gather<<<(N_NODES + 3) / 4, 256, 0, stream>>>(rowstart, csr_src, dinv, p2, b2, out);
}

// Round 3
// 988.511 us; speedup vs baseline: 1.7669x; 1.0969x over previous
//
#include <hip/hip_runtime.h>

#define N_NODES 100000
#define N_EDGES 3200000
#define NPASS 8
#define PRANGE ((N_NODES + NPASS - 1) / NPASS)  // 12500

// ---------------- CSR build ----------------

__global__ void k_hist_zero(int* __restrict__ hist) {
    int i = blockIdx.x * blockDim.x + threadIdx.x;
    if (i < N_NODES) hist[i] = 0;
}

__global__ void k_hist4(const int4* __restrict__ dst4, int* __restrict__ hist) {
    int i = blockIdx.x * blockDim.x + threadIdx.x;
    if (i < N_EDGES / 4) {
        int4 d = dst4[i];
        atomicAdd(&hist[d.x], 1);
        atomicAdd(&hist[d.y], 1);
        atomicAdd(&hist[d.z], 1);
        atomicAdd(&hist[d.w], 1);
    }
}

// single block of 1024: exclusive scan of hist -> rowstart, rowstart[N]=E
__global__ void k_scan(const int* __restrict__ hist, int* __restrict__ rowstart) {
    __shared__ int part[1024];
    int tid = threadIdx.x;
    const int CH = (N_NODES + 1023) / 1024;  // 98
    int begI = tid * CH;
    int endI = begI + CH;
    if (endI > N_NODES) endI = N_NODES;
    int sum = 0;
    for (int i = begI; i < endI; ++i) sum += hist[i];
    part[tid] = sum;
    __syncthreads();
    for (int off = 1; off < 1024; off <<= 1) {
        int v = (tid >= off) ? part[tid - off] : 0;
        __syncthreads();
        part[tid] += v;
        __syncthreads();
    }
    int run = (tid == 0) ? 0 : part[tid - 1];
    for (int i = begI; i < endI; ++i) {
        rowstart[i] = run;
        run += hist[i];
    }
    if (tid == 1023) rowstart[N_NODES] = run;
}

// dinv = rsqrt(in_degree + 1 self-loop); cursor = rowstart copy
__global__ void k_dinv_cursor(const int* __restrict__ hist, const int* __restrict__ rowstart,
                              float* __restrict__ dinv, int* __restrict__ cursor) {
    int i = blockIdx.x * blockDim.x + threadIdx.x;
    if (i < N_NODES) {
        dinv[i] = rsqrtf((float)(hist[i] + 1));
        cursor[i] = rowstart[i];
    }
}

// bucketed scatter: only edges with dst in [lo,hi) this pass -> localized writes
__global__ void k_scatter_pass(const int4* __restrict__ src4, const int4* __restrict__ dst4,
                               int* __restrict__ cursor, int* __restrict__ csr_src,
                               int lo, int hi) {
    int i = blockIdx.x * blockDim.x + threadIdx.x;
    if (i >= N_EDGES / 4) return;
    int4 d = dst4[i];
    int4 s = src4[i];
    if (d.x >= lo && d.x < hi) csr_src[atomicAdd(&cursor[d.x], 1)] = s.x;
    if (d.y >= lo && d.y < hi) csr_src[atomicAdd(&cursor[d.y], 1)] = s.y;
    if (d.z >= lo && d.z < hi) csr_src[atomicAdd(&cursor[d.z], 1)] = s.z;
    if (d.w >= lo && d.w < hi) csr_src[atomicAdd(&cursor[d.w], 1)] = s.w;
}

// ---------------- feature scaling: out[i][f] = dinv[i] * in[i][f] ----------------

__global__ void k_scale4(const float4* __restrict__ in, const float* __restrict__ dinv,
                         float4* __restrict__ out) {
    long long t = (long long)blockIdx.x * blockDim.x + threadIdx.x;
    if (t >= (long long)N_NODES * 16) return;
    float d = dinv[(int)(t >> 4)];
    float4 v = in[t];
    v.x *= d; v.y *= d; v.z *= d; v.w *= d;
    out[t] = v;
}

// ---------------- gather aggregation ----------------
// out[d][f] = dinv[d] * (xs[d][f] + sum_{s in in(d)} xs[s][f]) + bias[f]
// one wave per node, lane = feature; 4 rows in flight

__global__ __launch_bounds__(256) void k_gather(
    const int* __restrict__ rowstart, const int* __restrict__ csr_src,
    const float* __restrict__ dinv, const float* __restrict__ xs,
    const float* __restrict__ bias, float* __restrict__ out)
{
    int node = blockIdx.x * 4 + (threadIdx.x >> 6);
    if (node >= N_NODES) return;
    int lane = threadIdx.x & 63;
    int beg = rowstart[node];
    int deg = rowstart[node + 1] - beg;
    float acc0 = xs[(long long)node * 64 + lane];  // self loop (pre-scaled)
    float acc1 = 0.f, acc2 = 0.f, acc3 = 0.f;
    for (int base = 0; base < deg; base += 64) {
        int rem = deg - base;
        if (rem > 64) rem = 64;
        int mye = (lane < rem) ? csr_src[beg + base + lane] : 0;  // coalesced
        int j = 0;
        for (; j + 3 < rem; j += 4) {
            int s0 = __shfl(mye, j);
            int s1 = __shfl(mye, j + 1);
            int s2 = __shfl(mye, j + 2);
            int s3 = __shfl(mye, j + 3);
            acc0 += xs[(long long)s0 * 64 + lane];
            acc1 += xs[(long long)s1 * 64 + lane];
            acc2 += xs[(long long)s2 * 64 + lane];
            acc3 += xs[(long long)s3 * 64 + lane];
        }
        for (; j < rem; ++j) {
            int s0 = __shfl(mye, j);
            acc0 += xs[(long long)s0 * 64 + lane];
        }
    }
    float d = dinv[node];
    float b = bias ? bias[lane] : 0.f;
    out[(long long)node * 64 + lane] = d * ((acc0 + acc1) + (acc2 + acc3)) + b;
}

// ---------------- fused GEMM: P = dinv * (relu(A@W1 + b1) @ W2) ----------------
// A: [N,64], W1: [64,128], W2: [128,64], P: [N,64] (pre-scaled by dinv for layer-2 gather)

#define GROWS 8
__global__ __launch_bounds__(256) void k_fused_gemm(
    const float* __restrict__ A, const float* __restrict__ W1,
    const float* __restrict__ b1, const float* __restrict__ W2,
    const float* __restrict__ dinv, float* __restrict__ P)
{
    __shared__ float sW1[64 * 128];   // 32KB
    __shared__ float sW2[128 * 64];   // 32KB
    __shared__ float sH[GROWS][128];
    __shared__ float sA[GROWS][64];
    int tid = threadIdx.x;
    for (int i = tid; i < 64 * 128; i += 256) sW1[i] = W1[i];
    for (int i = tid; i < 128 * 64; i += 256) sW2[i] = W2[i];
    int r0 = blockIdx.x * GROWS;
    for (int i = tid; i < GROWS * 64; i += 256) {
        int rr = i >> 6;
        int row = r0 + rr;
        sA[rr][i & 63] = (row < N_NODES) ? A[(long long)row * 64 + (i & 63)] : 0.f;
    }
    __syncthreads();
    // phase 1: H = relu(A@W1 + b1)
    {
        int j = tid & 127;
        int rbase = (tid >> 7) * (GROWS / 2);
        float bb = b1[j];
        for (int rr = rbase; rr < rbase + GROWS / 2; ++rr) {
            float acc = bb;
#pragma unroll
            for (int k = 0; k < 64; ++k) acc += sA[rr][k] * sW1[k * 128 + j];
            sH[rr][j] = fmaxf(acc, 0.f);
        }
    }
    __syncthreads();
    // phase 2: P = dinv * (H@W2)
    {
        int j = tid & 63;
        int rbase = (tid >> 6) * (GROWS / 4);
        for (int rr = rbase; rr < rbase + GROWS / 4; ++rr) {
            int row = r0 + rr;
            if (row >= N_NODES) continue;
            float acc = 0.f;
#pragma unroll
            for (int k = 0; k < 128; ++k) acc += sH[rr][k] * sW2[k * 64 + j];
            P[(long long)row * 64 + j] = dinv[row] * acc;
        }
    }
}

// ---------------- launch ----------------

extern "C" void kernel_launch(void* const* d_in, const int* in_sizes, int n_in,
                              void* d_out, int out_size, void* d_ws, size_t ws_size,
                              hipStream_t stream) {
    const float* x  = (const float*)d_in[0];
    const int*   ei = (const int*)d_in[1];
    const float* W1 = (const float*)d_in[2];
    const float* b1 = (const float*)d_in[3];
    const float* W2 = (const float*)d_in[4];
    const float* b2 = (const float*)d_in[5];
    float* out = (float*)d_out;

    const int* srcE = ei;            // edge_index[0]
    const int* dstE = ei + N_EDGES;  // edge_index[1]

    // workspace layout
    char* w = (char*)d_ws;
    int*   hist     = (int*)w;                          w += sizeof(int) * N_NODES;
    int*   rowstart = (int*)w;                          w += sizeof(int) * (N_NODES + 1);
    int*   cursor   = (int*)w;                          w += sizeof(int) * N_NODES;
    int*   csr_src  = (int*)w;                          w += sizeof(int) * N_EDGES;
    float* dinv     = (float*)w;                        w += sizeof(float) * N_NODES;
    float* xs       = (float*)w;                        w += sizeof(float) * (size_t)N_NODES * 64;
    float* agg1     = (float*)w;                        w += sizeof(float) * (size_t)N_NODES * 64;
    float* p2 = xs;  // xs dead after layer-1 gather

    const int B = 256;
    int gN  = (N_NODES + B - 1) / B;
    int gE4 = (N_EDGES / 4 + B - 1) / B;
    int gNF4 = (int)(((long long)N_NODES * 16 + B - 1) / B);

    // CSR build + dinv
    k_hist_zero<<<gN, B, 0, stream>>>(hist);
    k_hist4<<<gE4, B, 0, stream>>>((const int4*)dstE, hist);
    k_scan<<<1, 1024, 0, stream>>>(hist, rowstart);
    k_dinv_cursor<<<gN, B, 0, stream>>>(hist, rowstart, dinv, cursor);
    for (int p = 0; p < NPASS; ++p) {
        int lo = p * PRANGE;
        int hi = lo + PRANGE;
        k_scatter_pass<<<gE4, B, 0, stream>>>((const int4*)srcE, (const int4*)dstE,
                                              cursor, csr_src, lo, hi);
    }

    // layer 1
    k_scale4<<<gNF4, B, 0, stream>>>((const float4*)x, dinv, (float4*)xs);
    k_gather<<<(N_NODES + 3) / 4, 256, 0, stream>>>(rowstart, csr_src, dinv, xs, nullptr, agg1);
    k_fused_gemm<<<(N_NODES + GROWS - 1) / GROWS, 256, 0, stream>>>(agg1, W1, b1, W2, dinv, p2);

    // layer 2: p2 already dinv-scaled; gather into out (+b2)
    k_gather<<<(N_NODES + 3) / 4, 256, 0, stream>>>(rowstart, csr_src, dinv, p2, b2, out);
}

// Round 4
// 710.118 us; speedup vs baseline: 2.4595x; 1.3920x over previous
//
#include <hip/hip_runtime.h>

#define N_NODES 100000
#define N_EDGES 3200000
#define NPASS 8
#define PRANGE ((N_NODES + NPASS - 1) / NPASS)  // 12500
#define SCAN_BLKS ((N_NODES + 1023) / 1024)     // 98

// ---------------- CSR build ----------------

__global__ void k_hist_zero(int* __restrict__ hist) {
    int i = blockIdx.x * blockDim.x + threadIdx.x;
    if (i < N_NODES) hist[i] = 0;
}

__global__ void k_hist4(const int4* __restrict__ dst4, int* __restrict__ hist) {
    int i = blockIdx.x * blockDim.x + threadIdx.x;
    if (i < N_EDGES / 4) {
        int4 d = dst4[i];
        atomicAdd(&hist[d.x], 1);
        atomicAdd(&hist[d.y], 1);
        atomicAdd(&hist[d.z], 1);
        atomicAdd(&hist[d.w], 1);
    }
}

// hierarchical exclusive scan of hist
__global__ __launch_bounds__(1024) void k_scan1(const int* __restrict__ hist,
                                                int* __restrict__ partial,
                                                int* __restrict__ bsum) {
    __shared__ int s[1024];
    int tid = threadIdx.x;
    int gi = blockIdx.x * 1024 + tid;
    int v = (gi < N_NODES) ? hist[gi] : 0;
    s[tid] = v;
    __syncthreads();
    for (int off = 1; off < 1024; off <<= 1) {
        int t = (tid >= off) ? s[tid - off] : 0;
        __syncthreads();
        s[tid] += t;
        __syncthreads();
    }
    if (gi < N_NODES) partial[gi] = s[tid] - v;  // exclusive within block
    if (tid == 1023) bsum[blockIdx.x] = s[1023];
}

__global__ void k_scan2(const int* __restrict__ bsum, int* __restrict__ bsumsc) {
    __shared__ int s[128];
    int tid = threadIdx.x;  // blockDim = 128
    int v = (tid < SCAN_BLKS) ? bsum[tid] : 0;
    s[tid] = v;
    __syncthreads();
    for (int off = 1; off < 128; off <<= 1) {
        int t = (tid >= off) ? s[tid - off] : 0;
        __syncthreads();
        s[tid] += t;
        __syncthreads();
    }
    if (tid < SCAN_BLKS) bsumsc[tid] = s[tid] - v;
}

__global__ void k_scan3(const int* __restrict__ hist, const int* __restrict__ partial,
                        const int* __restrict__ bsumsc,
                        int* __restrict__ rowstart, int* __restrict__ cursor,
                        float* __restrict__ dinv) {
    int i = blockIdx.x * blockDim.x + threadIdx.x;
    if (i < N_NODES) {
        int rs = partial[i] + bsumsc[i >> 10];
        rowstart[i] = rs;
        cursor[i] = rs;
        dinv[i] = rsqrtf((float)(hist[i] + 1));
        if (i == 0) rowstart[N_NODES] = N_EDGES;
    }
}

// bucketed scatter: only edges with dst in [lo,hi) this pass -> localized writes
__global__ void k_scatter_pass(const int4* __restrict__ src4, const int4* __restrict__ dst4,
                               int* __restrict__ cursor, int* __restrict__ csr_src,
                               int lo, int hi) {
    int i = blockIdx.x * blockDim.x + threadIdx.x;
    if (i >= N_EDGES / 4) return;
    int4 d = dst4[i];
    int4 s = src4[i];
    if (d.x >= lo && d.x < hi) csr_src[atomicAdd(&cursor[d.x], 1)] = s.x;
    if (d.y >= lo && d.y < hi) csr_src[atomicAdd(&cursor[d.y], 1)] = s.y;
    if (d.z >= lo && d.z < hi) csr_src[atomicAdd(&cursor[d.z], 1)] = s.z;
    if (d.w >= lo && d.w < hi) csr_src[atomicAdd(&cursor[d.w], 1)] = s.w;
}

// ---------------- feature scaling: out[i][f] = dinv[i] * in[i][f] ----------------

__global__ void k_scale4(const float4* __restrict__ in, const float* __restrict__ dinv,
                         float4* __restrict__ out) {
    long long t = (long long)blockIdx.x * blockDim.x + threadIdx.x;
    if (t >= (long long)N_NODES * 16) return;
    float d = dinv[(int)(t >> 4)];
    float4 v = in[t];
    v.x *= d; v.y *= d; v.z *= d; v.w *= d;
    out[t] = v;
}

// ---------------- gather aggregation (float4 lanes, 4 rows in flight) ----------------
// out[d][:] = dinv[d] * (xs[d][:] + sum_{s in in(d)} xs[s][:]) + bias

__global__ __launch_bounds__(256) void k_gather4(
    const int* __restrict__ rowstart, const int* __restrict__ csr_src,
    const float* __restrict__ dinv, const float4* __restrict__ xs4,
    const float4* __restrict__ bias4, float4* __restrict__ out4)
{
    int node = blockIdx.x * 4 + (threadIdx.x >> 6);
    if (node >= N_NODES) return;
    int lane = threadIdx.x & 63;
    int qlane = lane & 15;   // float4 slot within the 64-float row
    int egrp = lane >> 4;    // 0..3: which edge of each group of 4
    int beg = rowstart[node];
    int deg = rowstart[node + 1] - beg;
    float4 acc = make_float4(0.f, 0.f, 0.f, 0.f);
    if (egrp == 0) acc = xs4[(long long)node * 16 + qlane];  // self loop (pre-scaled)
    for (int base = 0; base < deg; base += 64) {
        int rem = deg - base;
        if (rem > 64) rem = 64;
        int mye = (lane < rem) ? csr_src[beg + base + lane] : 0;  // coalesced
        int nj = (rem + 3) >> 2;
        for (int j = 0; j < nj; ++j) {
            int eidx = (j << 2) + egrp;
            int s = __shfl(mye, eidx);
            if (eidx < rem) {
                float4 v = xs4[(long long)s * 16 + qlane];
                acc.x += v.x; acc.y += v.y; acc.z += v.z; acc.w += v.w;
            }
        }
    }
    // reduce the 4 edge-groups
    acc.x += __shfl_xor(acc.x, 16); acc.y += __shfl_xor(acc.y, 16);
    acc.z += __shfl_xor(acc.z, 16); acc.w += __shfl_xor(acc.w, 16);
    acc.x += __shfl_xor(acc.x, 32); acc.y += __shfl_xor(acc.y, 32);
    acc.z += __shfl_xor(acc.z, 32); acc.w += __shfl_xor(acc.w, 32);
    if (egrp == 0) {
        float d = dinv[node];
        float4 b = bias4 ? bias4[qlane] : make_float4(0.f, 0.f, 0.f, 0.f);
        float4 o;
        o.x = d * acc.x + b.x;
        o.y = d * acc.y + b.y;
        o.z = d * acc.z + b.z;
        o.w = d * acc.w + b.w;
        out4[(long long)node * 16 + qlane] = o;
    }
}

// ---------------- fused GEMM: P = dinv * (relu(A@W1 + b1) @ W2) ----------------
// register-tiled; A^T then H^T share one 64KB LDS buffer

#define GTILE 128
__global__ __launch_bounds__(256) void k_fused_gemm(
    const float* __restrict__ A, const float* __restrict__ W1,
    const float* __restrict__ b1, const float* __restrict__ W2,
    const float* __restrict__ dinv, float* __restrict__ P)
{
    __shared__ float sBuf[128][GTILE];  // rows 0..63: A^T[k][r]; later 0..127: H^T[c][r]
    int tid = threadIdx.x;
    int R0 = blockIdx.x * GTILE;

    // stage A transposed: thread t -> row t>>1, k-range (t&1)*32 .. +31
    {
        int row = tid >> 1;
        int kb = (tid & 1) * 32;
        int grow = R0 + row;
        if (grow < N_NODES) {
            const float4* src = (const float4*)&A[(long long)grow * 64 + kb];
#pragma unroll
            for (int q = 0; q < 8; ++q) {
                float4 v = src[q];
                int k = kb + q * 4;
                sBuf[k + 0][row] = v.x;
                sBuf[k + 1][row] = v.y;
                sBuf[k + 2][row] = v.z;
                sBuf[k + 3][row] = v.w;
            }
        } else {
#pragma unroll
            for (int q = 0; q < 8; ++q) {
                int k = kb + q * 4;
                sBuf[k + 0][row] = 0.f; sBuf[k + 1][row] = 0.f;
                sBuf[k + 2][row] = 0.f; sBuf[k + 3][row] = 0.f;
            }
        }
    }
    __syncthreads();

    int rg = tid & 15;
    int cg = tid >> 4;
    int r0 = rg * 8;

    // phase 1: acc[8][8] = A(r0..r0+7) @ W1(:, c0..c0+7)
    float acc[8][8];
#pragma unroll
    for (int i = 0; i < 8; ++i)
#pragma unroll
        for (int j = 0; j < 8; ++j) acc[i][j] = 0.f;
    {
        int c0 = cg * 8;
#pragma unroll 4
        for (int k = 0; k < 64; ++k) {
            float4 a0 = *(const float4*)&sBuf[k][r0];
            float4 a1 = *(const float4*)&sBuf[k][r0 + 4];
            float4 w0 = *(const float4*)&W1[k * 128 + c0];
            float4 w1 = *(const float4*)&W1[k * 128 + c0 + 4];
            float av[8] = {a0.x, a0.y, a0.z, a0.w, a1.x, a1.y, a1.z, a1.w};
            float wv[8] = {w0.x, w0.y, w0.z, w0.w, w1.x, w1.y, w1.z, w1.w};
#pragma unroll
            for (int i = 0; i < 8; ++i)
#pragma unroll
                for (int j = 0; j < 8; ++j) acc[i][j] += av[i] * wv[j];
        }
    }
    __syncthreads();  // all phase-1 A^T reads done before overwriting sBuf with H^T

    // bias + relu, write H^T (c-major) into sBuf
    {
        int c0 = cg * 8;
#pragma unroll
        for (int j = 0; j < 8; ++j) {
            float bb = b1[c0 + j];
            float4 h0, h1;
            h0.x = fmaxf(acc[0][j] + bb, 0.f);
            h0.y = fmaxf(acc[1][j] + bb, 0.f);
            h0.z = fmaxf(acc[2][j] + bb, 0.f);
            h0.w = fmaxf(acc[3][j] + bb, 0.f);
            h1.x = fmaxf(acc[4][j] + bb, 0.f);
            h1.y = fmaxf(acc[5][j] + bb, 0.f);
            h1.z = fmaxf(acc[6][j] + bb, 0.f);
            h1.w = fmaxf(acc[7][j] + bb, 0.f);
            *(float4*)&sBuf[c0 + j][r0] = h0;
            *(float4*)&sBuf[c0 + j][r0 + 4] = h1;
        }
    }
    __syncthreads();

    // phase 2: P(r0..r0+7, c0..c0+3) = dinv * (H @ W2)
    {
        int c0 = cg * 4;
        float acc2[8][4];
#pragma unroll
        for (int i = 0; i < 8; ++i)
#pragma unroll
            for (int j = 0; j < 4; ++j) acc2[i][j] = 0.f;
#pragma unroll 4
        for (int k = 0; k < 128; ++k) {
            float4 a0 = *(const float4*)&sBuf[k][r0];
            float4 a1 = *(const float4*)&sBuf[k][r0 + 4];
            float4 w = *(const float4*)&W2[k * 64 + c0];
            float av[8] = {a0.x, a0.y, a0.z, a0.w, a1.x, a1.y, a1.z, a1.w};
            float wv[4] = {w.x, w.y, w.z, w.w};
#pragma unroll
            for (int i = 0; i < 8; ++i)
#pragma unroll
                for (int j = 0; j < 4; ++j) acc2[i][j] += av[i] * wv[j];
        }
#pragma unroll
        for (int i = 0; i < 8; ++i) {
            int row = R0 + r0 + i;
            if (row < N_NODES) {
                float d = dinv[row];
                float4 o;
                o.x = d * acc2[i][0];
                o.y = d * acc2[i][1];
                o.z = d * acc2[i][2];
                o.w = d * acc2[i][3];
                *(float4*)&P[(long long)row * 64 + c0] = o;
            }
        }
    }
}

// ---------------- launch ----------------

extern "C" void kernel_launch(void* const* d_in, const int* in_sizes, int n_in,
                              void* d_out, int out_size, void* d_ws, size_t ws_size,
                              hipStream_t stream) {
    const float* x  = (const float*)d_in[0];
    const int*   ei = (const int*)d_in[1];
    const float* W1 = (const float*)d_in[2];
    const float* b1 = (const float*)d_in[3];
    const float* W2 = (const float*)d_in[4];
    const float* b2 = (const float*)d_in[5];
    float* out = (float*)d_out;

    const int* srcE = ei;            // edge_index[0]
    const int* dstE = ei + N_EDGES;  // edge_index[1]

    // workspace layout
    char* w = (char*)d_ws;
    int*   hist     = (int*)w;   w += sizeof(int) * N_NODES;
    int*   rowstart = (int*)w;   w += sizeof(int) * (N_NODES + 1);
    int*   cursor   = (int*)w;   w += sizeof(int) * N_NODES;
    int*   partial  = (int*)w;   w += sizeof(int) * N_NODES;
    int*   bsum     = (int*)w;   w += sizeof(int) * 128;
    int*   bsumsc   = (int*)w;   w += sizeof(int) * 128;
    int*   csr_src  = (int*)w;   w += sizeof(int) * N_EDGES;
    float* dinv     = (float*)w; w += sizeof(float) * N_NODES;
    float* xs       = (float*)w; w += sizeof(float) * (size_t)N_NODES * 64;
    float* agg1     = (float*)w; w += sizeof(float) * (size_t)N_NODES * 64;
    float* p2 = xs;  // xs dead after layer-1 gather

    const int B = 256;
    int gN   = (N_NODES + B - 1) / B;
    int gE4  = (N_EDGES / 4 + B - 1) / B;
    int gNF4 = (int)(((long long)N_NODES * 16 + B - 1) / B);

    // CSR build + dinv
    k_hist_zero<<<gN, B, 0, stream>>>(hist);
    k_hist4<<<gE4, B, 0, stream>>>((const int4*)dstE, hist);
    k_scan1<<<SCAN_BLKS, 1024, 0, stream>>>(hist, partial, bsum);
    k_scan2<<<1, 128, 0, stream>>>(bsum, bsumsc);
    k_scan3<<<gN, B, 0, stream>>>(hist, partial, bsumsc, rowstart, cursor, dinv);
    for (int p = 0; p < NPASS; ++p) {
        int lo = p * PRANGE;
        int hi = lo + PRANGE;
        k_scatter_pass<<<gE4, B, 0, stream>>>((const int4*)srcE, (const int4*)dstE,
                                              cursor, csr_src, lo, hi);
    }

    // layer 1
    k_scale4<<<gNF4, B, 0, stream>>>((const float4*)x, dinv, (float4*)xs);
    k_gather4<<<(N_NODES + 3) / 4, 256, 0, stream>>>(rowstart, csr_src, dinv,
                                                     (const float4*)xs, nullptr,
                                                     (float4*)agg1);
    k_fused_gemm<<<(N_NODES + GTILE - 1) / GTILE, 256, 0, stream>>>(agg1, W1, b1, W2, dinv, p2);

    // layer 2: p2 already dinv-scaled; gather into out (+b2)
    k_gather4<<<(N_NODES + 3) / 4, 256, 0, stream>>>(rowstart, csr_src, dinv,
                                                     (const float4*)p2, (const float4*)b2,
                                                     (float4*)out);
}

// Round 5
// 585.577 us; speedup vs baseline: 2.9826x; 1.2127x over previous
//
#include <hip/hip_runtime.h>
#include <hip/hip_fp16.h>

#define N_NODES 100000
#define N_EDGES 3200000
#define NPASS 4
#define PRANGE ((N_NODES + NPASS - 1) / NPASS)  // 25000
#define SCAN_BLKS ((N_NODES + 1023) / 1024)     // 98

struct alignas(8) Half4 { __half2 lo, hi; };

// ---------------- CSR build ----------------

__global__ void k_hist_zero(int* __restrict__ hist) {
    int i = blockIdx.x * blockDim.x + threadIdx.x;
    if (i < N_NODES) hist[i] = 0;
}

__global__ void k_hist4(const int4* __restrict__ dst4, int* __restrict__ hist) {
    int i = blockIdx.x * blockDim.x + threadIdx.x;
    if (i < N_EDGES / 4) {
        int4 d = dst4[i];
        atomicAdd(&hist[d.x], 1);
        atomicAdd(&hist[d.y], 1);
        atomicAdd(&hist[d.z], 1);
        atomicAdd(&hist[d.w], 1);
    }
}

// hierarchical exclusive scan of hist
__global__ __launch_bounds__(1024) void k_scan1(const int* __restrict__ hist,
                                                int* __restrict__ partial,
                                                int* __restrict__ bsum) {
    __shared__ int s[1024];
    int tid = threadIdx.x;
    int gi = blockIdx.x * 1024 + tid;
    int v = (gi < N_NODES) ? hist[gi] : 0;
    s[tid] = v;
    __syncthreads();
    for (int off = 1; off < 1024; off <<= 1) {
        int t = (tid >= off) ? s[tid - off] : 0;
        __syncthreads();
        s[tid] += t;
        __syncthreads();
    }
    if (gi < N_NODES) partial[gi] = s[tid] - v;  // exclusive within block
    if (tid == 1023) bsum[blockIdx.x] = s[1023];
}

__global__ void k_scan2(const int* __restrict__ bsum, int* __restrict__ bsumsc) {
    __shared__ int s[128];
    int tid = threadIdx.x;  // blockDim = 128
    int v = (tid < SCAN_BLKS) ? bsum[tid] : 0;
    s[tid] = v;
    __syncthreads();
    for (int off = 1; off < 128; off <<= 1) {
        int t = (tid >= off) ? s[tid - off] : 0;
        __syncthreads();
        s[tid] += t;
        __syncthreads();
    }
    if (tid < SCAN_BLKS) bsumsc[tid] = s[tid] - v;
}

__global__ void k_scan3(const int* __restrict__ hist, const int* __restrict__ partial,
                        const int* __restrict__ bsumsc,
                        int* __restrict__ rowstart, int* __restrict__ cursor,
                        float* __restrict__ dinv) {
    int i = blockIdx.x * blockDim.x + threadIdx.x;
    if (i < N_NODES) {
        int rs = partial[i] + bsumsc[i >> 10];
        rowstart[i] = rs;
        cursor[i] = rs;
        dinv[i] = rsqrtf((float)(hist[i] + 1));
        if (i == 0) rowstart[N_NODES] = N_EDGES;
    }
}

// bucketed scatter: only edges with dst in [lo,hi) this pass -> localized writes
__global__ void k_scatter_pass(const int4* __restrict__ src4, const int4* __restrict__ dst4,
                               int* __restrict__ cursor, int* __restrict__ csr_src,
                               int lo, int hi) {
    int i = blockIdx.x * blockDim.x + threadIdx.x;
    if (i >= N_EDGES / 4) return;
    int4 d = dst4[i];
    int4 s = src4[i];
    if (d.x >= lo && d.x < hi) csr_src[atomicAdd(&cursor[d.x], 1)] = s.x;
    if (d.y >= lo && d.y < hi) csr_src[atomicAdd(&cursor[d.y], 1)] = s.y;
    if (d.z >= lo && d.z < hi) csr_src[atomicAdd(&cursor[d.z], 1)] = s.z;
    if (d.w >= lo && d.w < hi) csr_src[atomicAdd(&cursor[d.w], 1)] = s.w;
}

// ---------------- feature scaling: xs[i][f] = fp16(dinv[i] * x[i][f]) ----------------

__global__ void k_scale_h4(const float4* __restrict__ in, const float* __restrict__ dinv,
                           Half4* __restrict__ out) {
    long long t = (long long)blockIdx.x * blockDim.x + threadIdx.x;
    if (t >= (long long)N_NODES * 16) return;
    float d = dinv[(int)(t >> 4)];
    float4 v = in[t];
    Half4 h;
    h.lo = __float22half2_rn(make_float2(v.x * d, v.y * d));
    h.hi = __float22half2_rn(make_float2(v.z * d, v.w * d));
    out[t] = h;
}

// ---------------- gather aggregation (fp16 in, f32 out) ----------------
// out[d][:] = dinv[d] * (xs[d][:] + sum_{s in in(d)} xs[s][:]) + bias
// one wave per node; 16 lanes per row (8B each), 4 edge-rows in flight

__global__ __launch_bounds__(256) void k_gather_h(
    const int* __restrict__ rowstart, const int* __restrict__ csr_src,
    const float* __restrict__ dinv, const Half4* __restrict__ xs4,
    const float4* __restrict__ bias4, float4* __restrict__ out4)
{
    int node = blockIdx.x * 4 + (threadIdx.x >> 6);
    if (node >= N_NODES) return;
    int lane = threadIdx.x & 63;
    int qlane = lane & 15;   // Half4 slot within the 64-half row
    int egrp = lane >> 4;    // 0..3: which edge of each group of 4
    int beg = rowstart[node];
    int deg = rowstart[node + 1] - beg;
    float4 acc = make_float4(0.f, 0.f, 0.f, 0.f);
    if (egrp == 0) {  // self loop (pre-scaled)
        Half4 v = xs4[(long long)node * 16 + qlane];
        float2 a = __half22float2(v.lo), b = __half22float2(v.hi);
        acc.x = a.x; acc.y = a.y; acc.z = b.x; acc.w = b.y;
    }
    for (int base = 0; base < deg; base += 64) {
        int rem = deg - base;
        if (rem > 64) rem = 64;
        int mye = (lane < rem) ? csr_src[beg + base + lane] : 0;  // coalesced
        int nj = (rem + 3) >> 2;
        for (int j = 0; j < nj; ++j) {
            int eidx = (j << 2) + egrp;
            int s = __shfl(mye, eidx);
            if (eidx < rem) {
                Half4 v = xs4[(long long)s * 16 + qlane];
                float2 a = __half22float2(v.lo), b = __half22float2(v.hi);
                acc.x += a.x; acc.y += a.y; acc.z += b.x; acc.w += b.y;
            }
        }
    }
    // reduce the 4 edge-groups
    acc.x += __shfl_xor(acc.x, 16); acc.y += __shfl_xor(acc.y, 16);
    acc.z += __shfl_xor(acc.z, 16); acc.w += __shfl_xor(acc.w, 16);
    acc.x += __shfl_xor(acc.x, 32); acc.y += __shfl_xor(acc.y, 32);
    acc.z += __shfl_xor(acc.z, 32); acc.w += __shfl_xor(acc.w, 32);
    if (egrp == 0) {
        float d = dinv[node];
        float4 b = bias4 ? bias4[qlane] : make_float4(0.f, 0.f, 0.f, 0.f);
        float4 o;
        o.x = d * acc.x + b.x;
        o.y = d * acc.y + b.y;
        o.z = d * acc.z + b.z;
        o.w = d * acc.w + b.w;
        out4[(long long)node * 16 + qlane] = o;
    }
}

// ---------------- fused GEMM: P = fp16(dinv * (relu(A@W1 + b1) @ W2)) ----------------
// register-tiled; A^T then H^T share one 64KB LDS buffer

#define GTILE 128
__global__ __launch_bounds__(256) void k_fused_gemm(
    const float* __restrict__ A, const float* __restrict__ W1,
    const float* __restrict__ b1, const float* __restrict__ W2,
    const float* __restrict__ dinv, Half4* __restrict__ P)
{
    __shared__ float sBuf[128][GTILE];  // rows 0..63: A^T[k][r]; later 0..127: H^T[c][r]
    int tid = threadIdx.x;
    int R0 = blockIdx.x * GTILE;

    // stage A transposed: thread t -> row t>>1, k-range (t&1)*32 .. +31
    {
        int row = tid >> 1;
        int kb = (tid & 1) * 32;
        int grow = R0 + row;
        if (grow < N_NODES) {
            const float4* src = (const float4*)&A[(long long)grow * 64 + kb];
#pragma unroll
            for (int q = 0; q < 8; ++q) {
                float4 v = src[q];
                int k = kb + q * 4;
                sBuf[k + 0][row] = v.x;
                sBuf[k + 1][row] = v.y;
                sBuf[k + 2][row] = v.z;
                sBuf[k + 3][row] = v.w;
            }
        } else {
#pragma unroll
            for (int q = 0; q < 8; ++q) {
                int k = kb + q * 4;
                sBuf[k + 0][row] = 0.f; sBuf[k + 1][row] = 0.f;
                sBuf[k + 2][row] = 0.f; sBuf[k + 3][row] = 0.f;
            }
        }
    }
    __syncthreads();

    int rg = tid & 15;
    int cg = tid >> 4;
    int r0 = rg * 8;

    // phase 1: acc[8][8] = A(r0..r0+7) @ W1(:, c0..c0+7)
    float acc[8][8];
#pragma unroll
    for (int i = 0; i < 8; ++i)
#pragma unroll
        for (int j = 0; j < 8; ++j) acc[i][j] = 0.f;
    {
        int c0 = cg * 8;
#pragma unroll 4
        for (int k = 0; k < 64; ++k) {
            float4 a0 = *(const float4*)&sBuf[k][r0];
            float4 a1 = *(const float4*)&sBuf[k][r0 + 4];
            float4 w0 = *(const float4*)&W1[k * 128 + c0];
            float4 w1 = *(const float4*)&W1[k * 128 + c0 + 4];
            float av[8] = {a0.x, a0.y, a0.z, a0.w, a1.x, a1.y, a1.z, a1.w};
            float wv[8] = {w0.x, w0.y, w0.z, w0.w, w1.x, w1.y, w1.z, w1.w};
#pragma unroll
            for (int i = 0; i < 8; ++i)
#pragma unroll
                for (int j = 0; j < 8; ++j) acc[i][j] += av[i] * wv[j];
        }
    }
    __syncthreads();  // all phase-1 A^T reads done before overwriting sBuf with H^T

    // bias + relu, write H^T (c-major) into sBuf
    {
        int c0 = cg * 8;
#pragma unroll
        for (int j = 0; j < 8; ++j) {
            float bb = b1[c0 + j];
            float4 h0, h1;
            h0.x = fmaxf(acc[0][j] + bb, 0.f);
            h0.y = fmaxf(acc[1][j] + bb, 0.f);
            h0.z = fmaxf(acc[2][j] + bb, 0.f);
            h0.w = fmaxf(acc[3][j] + bb, 0.f);
            h1.x = fmaxf(acc[4][j] + bb, 0.f);
            h1.y = fmaxf(acc[5][j] + bb, 0.f);
            h1.z = fmaxf(acc[6][j] + bb, 0.f);
            h1.w = fmaxf(acc[7][j] + bb, 0.f);
            *(float4*)&sBuf[c0 + j][r0] = h0;
            *(float4*)&sBuf[c0 + j][r0 + 4] = h1;
        }
    }
    __syncthreads();

    // phase 2: P(r0..r0+7, c0..c0+3) = fp16(dinv * (H @ W2))
    {
        int c0 = cg * 4;
        float acc2[8][4];
#pragma unroll
        for (int i = 0; i < 8; ++i)
#pragma unroll
            for (int j = 0; j < 4; ++j) acc2[i][j] = 0.f;
#pragma unroll 4
        for (int k = 0; k < 128; ++k) {
            float4 a0 = *(const float4*)&sBuf[k][r0];
            float4 a1 = *(const float4*)&sBuf[k][r0 + 4];
            float4 w = *(const float4*)&W2[k * 64 + c0];
            float av[8] = {a0.x, a0.y, a0.z, a0.w, a1.x, a1.y, a1.z, a1.w};
            float wv[4] = {w.x, w.y, w.z, w.w};
#pragma unroll
            for (int i = 0; i < 8; ++i)
#pragma unroll
                for (int j = 0; j < 4; ++j) acc2[i][j] += av[i] * wv[j];
        }
#pragma unroll
        for (int i = 0; i < 8; ++i) {
            int row = R0 + r0 + i;
            if (row < N_NODES) {
                float d = dinv[row];
                Half4 h;
                h.lo = __float22half2_rn(make_float2(d * acc2[i][0], d * acc2[i][1]));
                h.hi = __float22half2_rn(make_float2(d * acc2[i][2], d * acc2[i][3]));
                P[(long long)row * 16 + cg] = h;
            }
        }
    }
}

// ---------------- launch ----------------

extern "C" void kernel_launch(void* const* d_in, const int* in_sizes, int n_in,
                              void* d_out, int out_size, void* d_ws, size_t ws_size,
                              hipStream_t stream) {
    const float* x  = (const float*)d_in[0];
    const int*   ei = (const int*)d_in[1];
    const float* W1 = (const float*)d_in[2];
    const float* b1 = (const float*)d_in[3];
    const float* W2 = (const float*)d_in[4];
    const float* b2 = (const float*)d_in[5];
    float* out = (float*)d_out;

    const int* srcE = ei;            // edge_index[0]
    const int* dstE = ei + N_EDGES;  // edge_index[1]

    // workspace layout
    char* w = (char*)d_ws;
    int*   hist     = (int*)w;   w += sizeof(int) * N_NODES;
    int*   rowstart = (int*)w;   w += sizeof(int) * (N_NODES + 1);
    int*   cursor   = (int*)w;   w += sizeof(int) * N_NODES;
    int*   partial  = (int*)w;   w += sizeof(int) * N_NODES;
    int*   bsum     = (int*)w;   w += sizeof(int) * 128;
    int*   bsumsc   = (int*)w;   w += sizeof(int) * 128;
    int*   csr_src  = (int*)w;   w += sizeof(int) * N_EDGES;
    float* dinv     = (float*)w; w += sizeof(float) * N_NODES;
    Half4* xs       = (Half4*)w; w += sizeof(Half4) * (size_t)N_NODES * 16;
    float* agg1     = (float*)w; w += sizeof(float) * (size_t)N_NODES * 64;
    Half4* p2 = xs;  // xs dead after layer-1 gather; reuse for fp16 p2

    const int B = 256;
    int gN   = (N_NODES + B - 1) / B;
    int gE4  = (N_EDGES / 4 + B - 1) / B;
    int gNF4 = (int)(((long long)N_NODES * 16 + B - 1) / B);

    // CSR build + dinv
    k_hist_zero<<<gN, B, 0, stream>>>(hist);
    k_hist4<<<gE4, B, 0, stream>>>((const int4*)dstE, hist);
    k_scan1<<<SCAN_BLKS, 1024, 0, stream>>>(hist, partial, bsum);
    k_scan2<<<1, 128, 0, stream>>>(bsum, bsumsc);
    k_scan3<<<gN, B, 0, stream>>>(hist, partial, bsumsc, rowstart, cursor, dinv);
    for (int p = 0; p < NPASS; ++p) {
        int lo = p * PRANGE;
        int hi = lo + PRANGE;
        k_scatter_pass<<<gE4, B, 0, stream>>>((const int4*)srcE, (const int4*)dstE,
                                              cursor, csr_src, lo, hi);
    }

    // layer 1
    k_scale_h4<<<gNF4, B, 0, stream>>>((const float4*)x, dinv, xs);
    k_gather_h<<<(N_NODES + 3) / 4, 256, 0, stream>>>(rowstart, csr_src, dinv,
                                                      xs, nullptr, (float4*)agg1);
    k_fused_gemm<<<(N_NODES + GTILE - 1) / GTILE, 256, 0, stream>>>(agg1, W1, b1, W2, dinv, p2);

    // layer 2: p2 already dinv-scaled fp16; gather into out (+b2)
    k_gather_h<<<(N_NODES + 3) / 4, 256, 0, stream>>>(rowstart, csr_src, dinv,
                                                      p2, (const float4*)b2, (float4*)out);
}

// Round 6
// 344.421 us; speedup vs baseline: 5.0710x; 1.7002x over previous
//
#include <hip/hip_runtime.h>
#include <hip/hip_fp16.h>

#define N_NODES 100000
#define N_EDGES 3200000

#define NBLK_P 320
#define SLICE4 (N_EDGES / 4 / NBLK_P)   // 2500 int4 per partition block (exact)
#define NBKT 256
#define BSHIFT 9                         // 512 nodes per coarse bucket
#define NBKT_USED ((N_NODES + 511) / 512)  // 196

struct alignas(8) Half4 { __half2 lo, hi; };

// ================= CSR build: two-level counting sort (no global atomics) =================

// Phase A: per-block coarse histogram (LDS), written non-atomically per block
__global__ __launch_bounds__(256) void k_coarse_hist(const int4* __restrict__ dst4,
                                                     int* __restrict__ blockHist) {
    __shared__ int h[NBKT];
    int t = threadIdx.x;
    h[t] = 0;
    __syncthreads();
    int base = blockIdx.x * SLICE4;
    for (int i = t; i < SLICE4; i += 256) {
        int4 d = dst4[base + i];
        atomicAdd(&h[d.x >> BSHIFT], 1);
        atomicAdd(&h[d.y >> BSHIFT], 1);
        atomicAdd(&h[d.z >> BSHIFT], 1);
        atomicAdd(&h[d.w >> BSHIFT], 1);
    }
    __syncthreads();
    blockHist[blockIdx.x * NBKT + t] = h[t];
}

// Phase A2: column scan -> per-(block,bucket) placement offsets + coarseStart
__global__ __launch_bounds__(256) void k_colscan(int* __restrict__ blockHist,
                                                 int* __restrict__ coarseStart) {
    __shared__ int s[NBKT];
    int t = threadIdx.x;
    int tot = 0;
    for (int b = 0; b < NBLK_P; ++b) tot += blockHist[b * NBKT + t];  // coalesced rows
    s[t] = tot;
    __syncthreads();
    for (int off = 1; off < NBKT; off <<= 1) {
        int v = (t >= off) ? s[t - off] : 0;
        __syncthreads();
        s[t] += v;
        __syncthreads();
    }
    int cs = s[t] - tot;  // exclusive
    coarseStart[t] = cs;
    if (t == NBKT - 1) coarseStart[NBKT] = s[t];  // == N_EDGES
    int run = cs;
    for (int b = 0; b < NBLK_P; ++b) {
        int v = blockHist[b * NBKT + t];
        blockHist[b * NBKT + t] = run;
        run += v;
    }
}

// Phase B: partition (src,dst) pairs into coarse-bucket-sorted order via LDS cursors
__global__ __launch_bounds__(256) void k_partition(const int4* __restrict__ src4,
                                                   const int4* __restrict__ dst4,
                                                   const int* __restrict__ blockHist,
                                                   int2* __restrict__ sorted) {
    __shared__ int cur[NBKT];
    int t = threadIdx.x;
    cur[t] = blockHist[blockIdx.x * NBKT + t];
    __syncthreads();
    int base = blockIdx.x * SLICE4;
    for (int i = t; i < SLICE4; i += 256) {
        int4 d = dst4[base + i];
        int4 s = src4[base + i];
        int p;
        p = atomicAdd(&cur[d.x >> BSHIFT], 1); sorted[p] = make_int2(s.x, d.x);
        p = atomicAdd(&cur[d.y >> BSHIFT], 1); sorted[p] = make_int2(s.y, d.y);
        p = atomicAdd(&cur[d.z >> BSHIFT], 1); sorted[p] = make_int2(s.z, d.z);
        p = atomicAdd(&cur[d.w >> BSHIFT], 1); sorted[p] = make_int2(s.w, d.w);
    }
}

// Phase C: per-bucket fine histogram + scan -> rowstart/dinv, then scatter srcs
__global__ __launch_bounds__(256) void k_fine(const int2* __restrict__ sorted,
                                              const int* __restrict__ coarseStart,
                                              int* __restrict__ rowstart,
                                              float* __restrict__ dinv,
                                              int* __restrict__ csr_src) {
    __shared__ int h[512];
    __shared__ int pairsc[256];
    __shared__ int offs[512];
    int t = threadIdx.x;
    int bkt = blockIdx.x;
    int beg = coarseStart[bkt], end = coarseStart[bkt + 1];
    h[t] = 0; h[t + 256] = 0;
    __syncthreads();
    for (int i = beg + t; i < end; i += 256) {
        int d = sorted[i].y;
        atomicAdd(&h[d & 511], 1);
    }
    __syncthreads();
    int pv = h[2 * t] + h[2 * t + 1];
    pairsc[t] = pv;
    __syncthreads();
    for (int off = 1; off < 256; off <<= 1) {
        int v = (t >= off) ? pairsc[t - off] : 0;
        __syncthreads();
        pairsc[t] += v;
        __syncthreads();
    }
    int e0 = pairsc[t] - pv;  // exclusive over pairs
    offs[2 * t] = e0;
    offs[2 * t + 1] = e0 + h[2 * t];
    __syncthreads();
    int n0 = bkt << BSHIFT;
#pragma unroll
    for (int q = 0; q < 2; ++q) {
        int local = t + q * 256;
        int node = n0 + local;
        if (node < N_NODES) {
            rowstart[node] = beg + offs[local];
            dinv[node] = rsqrtf((float)(h[local] + 1));
        }
    }
    if (bkt == 0 && t == 0) rowstart[N_NODES] = N_EDGES;
    __syncthreads();
    for (int i = beg + t; i < end; i += 256) {
        int2 e = sorted[i];
        int p = atomicAdd(&offs[e.y & 511], 1);
        csr_src[beg + p] = e.x;
    }
}

// ---------------- feature scaling: xs[i][f] = fp16(dinv[i] * x[i][f]) ----------------

__global__ void k_scale_h4(const float4* __restrict__ in, const float* __restrict__ dinv,
                           Half4* __restrict__ out) {
    long long t = (long long)blockIdx.x * blockDim.x + threadIdx.x;
    if (t >= (long long)N_NODES * 16) return;
    float d = dinv[(int)(t >> 4)];
    float4 v = in[t];
    Half4 h;
    h.lo = __float22half2_rn(make_float2(v.x * d, v.y * d));
    h.hi = __float22half2_rn(make_float2(v.z * d, v.w * d));
    out[t] = h;
}

// ---------------- gather aggregation (fp16 in, f32 out) ----------------

__global__ __launch_bounds__(256) void k_gather_h(
    const int* __restrict__ rowstart, const int* __restrict__ csr_src,
    const float* __restrict__ dinv, const Half4* __restrict__ xs4,
    const float4* __restrict__ bias4, float4* __restrict__ out4)
{
    int node = blockIdx.x * 4 + (threadIdx.x >> 6);
    if (node >= N_NODES) return;
    int lane = threadIdx.x & 63;
    int qlane = lane & 15;   // Half4 slot within the 64-half row
    int egrp = lane >> 4;    // 0..3: which edge of each group of 4
    int beg = rowstart[node];
    int deg = rowstart[node + 1] - beg;
    float4 acc = make_float4(0.f, 0.f, 0.f, 0.f);
    if (egrp == 0) {  // self loop (pre-scaled)
        Half4 v = xs4[(long long)node * 16 + qlane];
        float2 a = __half22float2(v.lo), b = __half22float2(v.hi);
        acc.x = a.x; acc.y = a.y; acc.z = b.x; acc.w = b.y;
    }
    for (int base = 0; base < deg; base += 64) {
        int rem = deg - base;
        if (rem > 64) rem = 64;
        int mye = (lane < rem) ? csr_src[beg + base + lane] : 0;  // coalesced
        int nj = (rem + 3) >> 2;
        for (int j = 0; j < nj; ++j) {
            int eidx = (j << 2) + egrp;
            int s = __shfl(mye, eidx);
            if (eidx < rem) {
                Half4 v = xs4[(long long)s * 16 + qlane];
                float2 a = __half22float2(v.lo), b = __half22float2(v.hi);
                acc.x += a.x; acc.y += a.y; acc.z += b.x; acc.w += b.y;
            }
        }
    }
    acc.x += __shfl_xor(acc.x, 16); acc.y += __shfl_xor(acc.y, 16);
    acc.z += __shfl_xor(acc.z, 16); acc.w += __shfl_xor(acc.w, 16);
    acc.x += __shfl_xor(acc.x, 32); acc.y += __shfl_xor(acc.y, 32);
    acc.z += __shfl_xor(acc.z, 32); acc.w += __shfl_xor(acc.w, 32);
    if (egrp == 0) {
        float d = dinv[node];
        float4 b = bias4 ? bias4[qlane] : make_float4(0.f, 0.f, 0.f, 0.f);
        float4 o;
        o.x = d * acc.x + b.x;
        o.y = d * acc.y + b.y;
        o.z = d * acc.z + b.z;
        o.w = d * acc.w + b.w;
        out4[(long long)node * 16 + qlane] = o;
    }
}

// ---------------- fused GEMM: P = fp16(dinv * (relu(A@W1 + b1) @ W2)) ----------------

#define GTILE 128
__global__ __launch_bounds__(256) void k_fused_gemm(
    const float* __restrict__ A, const float* __restrict__ W1,
    const float* __restrict__ b1, const float* __restrict__ W2,
    const float* __restrict__ dinv, Half4* __restrict__ P)
{
    __shared__ float sBuf[128][GTILE];  // rows 0..63: A^T[k][r]; later 0..127: H^T[c][r]
    int tid = threadIdx.x;
    int R0 = blockIdx.x * GTILE;

    {
        int row = tid >> 1;
        int kb = (tid & 1) * 32;
        int grow = R0 + row;
        if (grow < N_NODES) {
            const float4* src = (const float4*)&A[(long long)grow * 64 + kb];
#pragma unroll
            for (int q = 0; q < 8; ++q) {
                float4 v = src[q];
                int k = kb + q * 4;
                sBuf[k + 0][row] = v.x;
                sBuf[k + 1][row] = v.y;
                sBuf[k + 2][row] = v.z;
                sBuf[k + 3][row] = v.w;
            }
        } else {
#pragma unroll
            for (int q = 0; q < 8; ++q) {
                int k = kb + q * 4;
                sBuf[k + 0][row] = 0.f; sBuf[k + 1][row] = 0.f;
                sBuf[k + 2][row] = 0.f; sBuf[k + 3][row] = 0.f;
            }
        }
    }
    __syncthreads();

    int rg = tid & 15;
    int cg = tid >> 4;
    int r0 = rg * 8;

    float acc[8][8];
#pragma unroll
    for (int i = 0; i < 8; ++i)
#pragma unroll
        for (int j = 0; j < 8; ++j) acc[i][j] = 0.f;
    {
        int c0 = cg * 8;
#pragma unroll 4
        for (int k = 0; k < 64; ++k) {
            float4 a0 = *(const float4*)&sBuf[k][r0];
            float4 a1 = *(const float4*)&sBuf[k][r0 + 4];
            float4 w0 = *(const float4*)&W1[k * 128 + c0];
            float4 w1 = *(const float4*)&W1[k * 128 + c0 + 4];
            float av[8] = {a0.x, a0.y, a0.z, a0.w, a1.x, a1.y, a1.z, a1.w};
            float wv[8] = {w0.x, w0.y, w0.z, w0.w, w1.x, w1.y, w1.z, w1.w};
#pragma unroll
            for (int i = 0; i < 8; ++i)
#pragma unroll
                for (int j = 0; j < 8; ++j) acc[i][j] += av[i] * wv[j];
        }
    }
    __syncthreads();

    {
        int c0 = cg * 8;
#pragma unroll
        for (int j = 0; j < 8; ++j) {
            float bb = b1[c0 + j];
            float4 h0, h1;
            h0.x = fmaxf(acc[0][j] + bb, 0.f);
            h0.y = fmaxf(acc[1][j] + bb, 0.f);
            h0.z = fmaxf(acc[2][j] + bb, 0.f);
            h0.w = fmaxf(acc[3][j] + bb, 0.f);
            h1.x = fmaxf(acc[4][j] + bb, 0.f);
            h1.y = fmaxf(acc[5][j] + bb, 0.f);
            h1.z = fmaxf(acc[6][j] + bb, 0.f);
            h1.w = fmaxf(acc[7][j] + bb, 0.f);
            *(float4*)&sBuf[c0 + j][r0] = h0;
            *(float4*)&sBuf[c0 + j][r0 + 4] = h1;
        }
    }
    __syncthreads();

    {
        int c0 = cg * 4;
        float acc2[8][4];
#pragma unroll
        for (int i = 0; i < 8; ++i)
#pragma unroll
            for (int j = 0; j < 4; ++j) acc2[i][j] = 0.f;
#pragma unroll 4
        for (int k = 0; k < 128; ++k) {
            float4 a0 = *(const float4*)&sBuf[k][r0];
            float4 a1 = *(const float4*)&sBuf[k][r0 + 4];
            float4 w = *(const float4*)&W2[k * 64 + c0];
            float av[8] = {a0.x, a0.y, a0.z, a0.w, a1.x, a1.y, a1.z, a1.w};
            float wv[4] = {w.x, w.y, w.z, w.w};
#pragma unroll
            for (int i = 0; i < 8; ++i)
#pragma unroll
                for (int j = 0; j < 4; ++j) acc2[i][j] += av[i] * wv[j];
        }
#pragma unroll
        for (int i = 0; i < 8; ++i) {
            int row = R0 + r0 + i;
            if (row < N_NODES) {
                float d = dinv[row];
                Half4 h;
                h.lo = __float22half2_rn(make_float2(d * acc2[i][0], d * acc2[i][1]));
                h.hi = __float22half2_rn(make_float2(d * acc2[i][2], d * acc2[i][3]));
                P[(long long)row * 16 + cg] = h;
            }
        }
    }
}

// ---------------- launch ----------------

extern "C" void kernel_launch(void* const* d_in, const int* in_sizes, int n_in,
                              void* d_out, int out_size, void* d_ws, size_t ws_size,
                              hipStream_t stream) {
    const float* x  = (const float*)d_in[0];
    const int*   ei = (const int*)d_in[1];
    const float* W1 = (const float*)d_in[2];
    const float* b1 = (const float*)d_in[3];
    const float* W2 = (const float*)d_in[4];
    const float* b2 = (const float*)d_in[5];
    float* out = (float*)d_out;

    const int* srcE = ei;            // edge_index[0]
    const int* dstE = ei + N_EDGES;  // edge_index[1]

    // workspace layout
    char* w = (char*)d_ws;
    int*   blockHist   = (int*)w;   w += sizeof(int) * NBLK_P * NBKT;
    int*   coarseStart = (int*)w;   w += sizeof(int) * (NBKT + 1);
    int*   rowstart    = (int*)w;   w += sizeof(int) * (N_NODES + 8);
    float* dinv        = (float*)w; w += sizeof(float) * (N_NODES + 8);
    int*   csr_src     = (int*)w;   w += sizeof(int) * N_EDGES;
    Half4* xs          = (Half4*)w; w += sizeof(Half4) * (size_t)N_NODES * 16;
    // union: sorted (E int2 = 25.6MB) dies before agg1 (N*64 f32 = 25.6MB) is written
    int2*  sorted      = (int2*)w;
    float* agg1        = (float*)w; w += sizeof(float) * (size_t)N_NODES * 64;
    Half4* p2 = xs;  // xs dead after layer-1 gather; reuse for fp16 p2

    const int B = 256;
    int gNF4 = (int)(((long long)N_NODES * 16 + B - 1) / B);

    // CSR build (no global atomics)
    k_coarse_hist<<<NBLK_P, 256, 0, stream>>>((const int4*)dstE, blockHist);
    k_colscan<<<1, 256, 0, stream>>>(blockHist, coarseStart);
    k_partition<<<NBLK_P, 256, 0, stream>>>((const int4*)srcE, (const int4*)dstE,
                                            blockHist, sorted);
    k_fine<<<NBKT_USED, 256, 0, stream>>>(sorted, coarseStart, rowstart, dinv, csr_src);

    // layer 1
    k_scale_h4<<<gNF4, B, 0, stream>>>((const float4*)x, dinv, xs);
    k_gather_h<<<(N_NODES + 3) / 4, 256, 0, stream>>>(rowstart, csr_src, dinv,
                                                      xs, nullptr, (float4*)agg1);
    k_fused_gemm<<<(N_NODES + GTILE - 1) / GTILE, 256, 0, stream>>>(agg1, W1, b1, W2, dinv, p2);

    // layer 2: p2 already dinv-scaled fp16; gather into out (+b2)
    k_gather_h<<<(N_NODES + 3) / 4, 256, 0, stream>>>(rowstart, csr_src, dinv,
                                                      p2, (const float4*)b2, (float4*)out);
}

// Round 7
// 314.000 us; speedup vs baseline: 5.5623x; 1.0969x over previous
//
#include <hip/hip_runtime.h>
#include <hip/hip_fp16.h>

#define N_NODES 100000
#define N_EDGES 3200000

#define NBLK_P 320
#define SLICE4 (N_EDGES / 4 / NBLK_P)      // 2500 int4 per partition block (exact)
#define NBKT 256
#define BSHIFT 9                            // 512 nodes per coarse bucket
#define NBKT_USED ((N_NODES + 511) / 512)   // 196
#define EL_CAP 24576                        // LDS edge cache (96 KB); mean bucket = 16384

struct alignas(8) Half4 { __half2 lo, hi; };

// ================= CSR build: two-level counting sort (no global atomics) =================
// packed edge int: src | (dst&511)<<17   (src<2^17, dloc<2^9)

__global__ __launch_bounds__(256) void k_coarse_hist(const int4* __restrict__ dst4,
                                                     int* __restrict__ blockHist) {
    __shared__ int h[NBKT];
    int t = threadIdx.x;
    h[t] = 0;
    __syncthreads();
    int base = blockIdx.x * SLICE4;
    for (int i = t; i < SLICE4; i += 256) {
        int4 d = dst4[base + i];
        atomicAdd(&h[d.x >> BSHIFT], 1);
        atomicAdd(&h[d.y >> BSHIFT], 1);
        atomicAdd(&h[d.z >> BSHIFT], 1);
        atomicAdd(&h[d.w >> BSHIFT], 1);
    }
    __syncthreads();
    blockHist[blockIdx.x * NBKT + t] = h[t];
}

// column scan: per-(block,bucket) placement offsets + coarseStart; 1024 thr (4 chunks x 256 buckets)
__global__ __launch_bounds__(1024) void k_colscan(int* __restrict__ blockHist,
                                                  int* __restrict__ coarseStart) {
    __shared__ int part[4][NBKT];
    __shared__ int s[NBKT];
    __shared__ int totA[NBKT];
    int tid = threadIdx.x;
    int b = tid & 255, q = tid >> 8;
    const int QR = NBLK_P / 4;  // 80
    int sum = 0;
    for (int r = q * QR; r < (q + 1) * QR; ++r) sum += blockHist[r * NBKT + b];
    part[q][b] = sum;
    __syncthreads();
    if (q == 0) {
        int tot = part[0][b] + part[1][b] + part[2][b] + part[3][b];
        s[b] = tot;
        totA[b] = tot;
    }
    __syncthreads();
    for (int off = 1; off < NBKT; off <<= 1) {
        int v = 0;
        if (q == 0 && b >= off) v = s[b - off];
        __syncthreads();
        if (q == 0) s[b] += v;
        __syncthreads();
    }
    int excl = s[b] - totA[b];
    if (q == 0) {
        coarseStart[b] = excl;
        if (b == 0) coarseStart[NBKT] = N_EDGES;
    }
    int run = excl;
    if (q > 0) run += part[0][b];
    if (q > 1) run += part[1][b];
    if (q > 2) run += part[2][b];
    for (int r = q * QR; r < (q + 1) * QR; ++r) {
        int v = blockHist[r * NBKT + b];
        blockHist[r * NBKT + b] = run;
        run += v;
    }
}

// partition packed edges into coarse-bucket-sorted order via LDS cursors
__global__ __launch_bounds__(256) void k_partition(const int4* __restrict__ src4,
                                                   const int4* __restrict__ dst4,
                                                   const int* __restrict__ blockHist,
                                                   int* __restrict__ sorted) {
    __shared__ int cur[NBKT];
    int t = threadIdx.x;
    cur[t] = blockHist[blockIdx.x * NBKT + t];
    __syncthreads();
    int base = blockIdx.x * SLICE4;
    for (int i = t; i < SLICE4; i += 256) {
        int4 d = dst4[base + i];
        int4 s = src4[base + i];
        int p;
        p = atomicAdd(&cur[d.x >> BSHIFT], 1); sorted[p] = s.x | ((d.x & 511) << 17);
        p = atomicAdd(&cur[d.y >> BSHIFT], 1); sorted[p] = s.y | ((d.y & 511) << 17);
        p = atomicAdd(&cur[d.z >> BSHIFT], 1); sorted[p] = s.z | ((d.z & 511) << 17);
        p = atomicAdd(&cur[d.w >> BSHIFT], 1); sorted[p] = s.w | ((d.w & 511) << 17);
    }
}

// per-bucket: LDS-staged fine hist + scan -> rowstart/dinv, scatter srcs, fused x->fp16 scale
__global__ __launch_bounds__(256) void k_fine(const int* __restrict__ sorted,
                                              const int* __restrict__ coarseStart,
                                              const float4* __restrict__ x4,
                                              int* __restrict__ rowstart,
                                              float* __restrict__ dinvg,
                                              int* __restrict__ csr_src,
                                              Half4* __restrict__ xs) {
    __shared__ int eL[EL_CAP];
    __shared__ int h[512];
    __shared__ int pairsc[256];
    __shared__ int offs[512];
    __shared__ float dloc[512];
    int t = threadIdx.x;
    int bkt = blockIdx.x;
    int beg = coarseStart[bkt], end = coarseStart[bkt + 1];
    int cnt = end - beg;
    bool inLds = (cnt <= EL_CAP);
    h[t] = 0; h[t + 256] = 0;
    __syncthreads();
    if (inLds) {
        for (int i = t; i < cnt; i += 256) eL[i] = sorted[beg + i];
        __syncthreads();
        for (int i = t; i < cnt; i += 256) atomicAdd(&h[eL[i] >> 17], 1);
    } else {
        for (int i = beg + t; i < end; i += 256) atomicAdd(&h[sorted[i] >> 17], 1);
    }
    __syncthreads();
    int pv = h[2 * t] + h[2 * t + 1];
    pairsc[t] = pv;
    __syncthreads();
    for (int off = 1; off < 256; off <<= 1) {
        int v = (t >= off) ? pairsc[t - off] : 0;
        __syncthreads();
        pairsc[t] += v;
        __syncthreads();
    }
    int e0 = pairsc[t] - pv;
    offs[2 * t] = e0;
    offs[2 * t + 1] = e0 + h[2 * t];
    __syncthreads();
    int n0 = bkt << BSHIFT;
    int nvalid = N_NODES - n0;
    if (nvalid > 512) nvalid = 512;
#pragma unroll
    for (int q = 0; q < 2; ++q) {
        int local = t + q * 256;
        if (local < nvalid) {
            rowstart[n0 + local] = beg + offs[local];
            float dv = rsqrtf((float)(h[local] + 1));
            dloc[local] = dv;
            dinvg[n0 + local] = dv;
        }
    }
    if (bkt == 0 && t == 0) rowstart[N_NODES] = N_EDGES;
    __syncthreads();
    // scatter srcs into csr_src (writes confined to [beg,end): L2-resident window)
    if (inLds) {
        for (int i = t; i < cnt; i += 256) {
            int pk = eL[i];
            int p = atomicAdd(&offs[pk >> 17], 1);
            csr_src[beg + p] = pk & 0x1FFFF;
        }
    } else {
        for (int i = beg + t; i < end; i += 256) {
            int pk = sorted[i];
            int p = atomicAdd(&offs[pk >> 17], 1);
            csr_src[beg + p] = pk & 0x1FFFF;
        }
    }
    // fused scale: xs[row] = fp16(dinv[row] * x[row]) for this bucket's rows
    for (int i = t; i < nvalid * 16; i += 256) {
        int local = i >> 4;
        int qq = i & 15;
        float d = dloc[local];
        float4 v = x4[(long long)(n0 + local) * 16 + qq];
        Half4 hh;
        hh.lo = __float22half2_rn(make_float2(v.x * d, v.y * d));
        hh.hi = __float22half2_rn(make_float2(v.z * d, v.w * d));
        xs[(long long)(n0 + local) * 16 + qq] = hh;
    }
}

// ---------------- gather aggregation (fp16 in, f32 out) ----------------
// 8 lanes per row (16B each), 8 edge-rows in flight per wave

__global__ __launch_bounds__(256) void k_gather_h(
    const int* __restrict__ rowstart, const int* __restrict__ csr_src,
    const float* __restrict__ dinv, const int4* __restrict__ xs16,
    const float4* __restrict__ bias4, float4* __restrict__ out4)
{
    int node = blockIdx.x * 4 + (threadIdx.x >> 6);
    if (node >= N_NODES) return;
    int lane = threadIdx.x & 63;
    int qlane = lane & 7;   // 16B slot within the 128B row
    int egrp = lane >> 3;   // 0..7: edge slot within each group of 8
    int beg = rowstart[node];
    int deg = rowstart[node + 1] - beg;
    float acc[8];
#pragma unroll
    for (int k = 0; k < 8; ++k) acc[k] = 0.f;
    if (egrp == 0) {  // self loop (pre-scaled)
        int4 v = xs16[((long long)node << 3) + qlane];
        float2 f0 = __half22float2(*(__half2*)&v.x);
        float2 f1 = __half22float2(*(__half2*)&v.y);
        float2 f2 = __half22float2(*(__half2*)&v.z);
        float2 f3 = __half22float2(*(__half2*)&v.w);
        acc[0] = f0.x; acc[1] = f0.y; acc[2] = f1.x; acc[3] = f1.y;
        acc[4] = f2.x; acc[5] = f2.y; acc[6] = f3.x; acc[7] = f3.y;
    }
    for (int base = 0; base < deg; base += 64) {
        int rem = deg - base;
        if (rem > 64) rem = 64;
        int mye = (lane < rem) ? csr_src[beg + base + lane] : 0;  // coalesced
        int nj = (rem + 7) >> 3;
        for (int j = 0; j < nj; ++j) {
            int eidx = (j << 3) + egrp;
            int s = __shfl(mye, eidx);
            if (eidx < rem) {
                int4 v = xs16[((long long)s << 3) + qlane];
                float2 f0 = __half22float2(*(__half2*)&v.x);
                float2 f1 = __half22float2(*(__half2*)&v.y);
                float2 f2 = __half22float2(*(__half2*)&v.z);
                float2 f3 = __half22float2(*(__half2*)&v.w);
                acc[0] += f0.x; acc[1] += f0.y; acc[2] += f1.x; acc[3] += f1.y;
                acc[4] += f2.x; acc[5] += f2.y; acc[6] += f3.x; acc[7] += f3.y;
            }
        }
    }
#pragma unroll
    for (int k = 0; k < 8; ++k) {
        acc[k] += __shfl_xor(acc[k], 8);
        acc[k] += __shfl_xor(acc[k], 16);
        acc[k] += __shfl_xor(acc[k], 32);
    }
    if (egrp == 0) {
        float d = dinv[node];
        float4 b0 = bias4 ? bias4[qlane * 2] : make_float4(0.f, 0.f, 0.f, 0.f);
        float4 b1 = bias4 ? bias4[qlane * 2 + 1] : make_float4(0.f, 0.f, 0.f, 0.f);
        out4[(long long)node * 16 + qlane * 2] =
            make_float4(d * acc[0] + b0.x, d * acc[1] + b0.y, d * acc[2] + b0.z, d * acc[3] + b0.w);
        out4[(long long)node * 16 + qlane * 2 + 1] =
            make_float4(d * acc[4] + b1.x, d * acc[5] + b1.y, d * acc[6] + b1.z, d * acc[7] + b1.w);
    }
}

// ---------------- fused GEMM: P = fp16(dinv * (relu(A@W1 + b1) @ W2)) ----------------

#define GTILE 128
__global__ __launch_bounds__(256) void k_fused_gemm(
    const float* __restrict__ A, const float* __restrict__ W1,
    const float* __restrict__ b1, const float* __restrict__ W2,
    const float* __restrict__ dinv, Half4* __restrict__ P)
{
    __shared__ float sBuf[128][GTILE];  // rows 0..63: A^T[k][r]; later 0..127: H^T[c][r]
    int tid = threadIdx.x;
    int R0 = blockIdx.x * GTILE;

    {
        int row = tid >> 1;
        int kb = (tid & 1) * 32;
        int grow = R0 + row;
        if (grow < N_NODES) {
            const float4* src = (const float4*)&A[(long long)grow * 64 + kb];
#pragma unroll
            for (int q = 0; q < 8; ++q) {
                float4 v = src[q];
                int k = kb + q * 4;
                sBuf[k + 0][row] = v.x;
                sBuf[k + 1][row] = v.y;
                sBuf[k + 2][row] = v.z;
                sBuf[k + 3][row] = v.w;
            }
        } else {
#pragma unroll
            for (int q = 0; q < 8; ++q) {
                int k = kb + q * 4;
                sBuf[k + 0][row] = 0.f; sBuf[k + 1][row] = 0.f;
                sBuf[k + 2][row] = 0.f; sBuf[k + 3][row] = 0.f;
            }
        }
    }
    __syncthreads();

    int rg = tid & 15;
    int cg = tid >> 4;
    int r0 = rg * 8;

    float acc[8][8];
#pragma unroll
    for (int i = 0; i < 8; ++i)
#pragma unroll
        for (int j = 0; j < 8; ++j) acc[i][j] = 0.f;
    {
        int c0 = cg * 8;
#pragma unroll 4
        for (int k = 0; k < 64; ++k) {
            float4 a0 = *(const float4*)&sBuf[k][r0];
            float4 a1 = *(const float4*)&sBuf[k][r0 + 4];
            float4 w0 = *(const float4*)&W1[k * 128 + c0];
            float4 w1 = *(const float4*)&W1[k * 128 + c0 + 4];
            float av[8] = {a0.x, a0.y, a0.z, a0.w, a1.x, a1.y, a1.z, a1.w};
            float wv[8] = {w0.x, w0.y, w0.z, w0.w, w1.x, w1.y, w1.z, w1.w};
#pragma unroll
            for (int i = 0; i < 8; ++i)
#pragma unroll
                for (int j = 0; j < 8; ++j) acc[i][j] += av[i] * wv[j];
        }
    }
    __syncthreads();

    {
        int c0 = cg * 8;
#pragma unroll
        for (int j = 0; j < 8; ++j) {
            float bb = b1[c0 + j];
            float4 h0, h1;
            h0.x = fmaxf(acc[0][j] + bb, 0.f);
            h0.y = fmaxf(acc[1][j] + bb, 0.f);
            h0.z = fmaxf(acc[2][j] + bb, 0.f);
            h0.w = fmaxf(acc[3][j] + bb, 0.f);
            h1.x = fmaxf(acc[4][j] + bb, 0.f);
            h1.y = fmaxf(acc[5][j] + bb, 0.f);
            h1.z = fmaxf(acc[6][j] + bb, 0.f);
            h1.w = fmaxf(acc[7][j] + bb, 0.f);
            *(float4*)&sBuf[c0 + j][r0] = h0;
            *(float4*)&sBuf[c0 + j][r0 + 4] = h1;
        }
    }
    __syncthreads();

    {
        int c0 = cg * 4;
        float acc2[8][4];
#pragma unroll
        for (int i = 0; i < 8; ++i)
#pragma unroll
            for (int j = 0; j < 4; ++j) acc2[i][j] = 0.f;
#pragma unroll 4
        for (int k = 0; k < 128; ++k) {
            float4 a0 = *(const float4*)&sBuf[k][r0];
            float4 a1 = *(const float4*)&sBuf[k][r0 + 4];
            float4 w = *(const float4*)&W2[k * 64 + c0];
            float av[8] = {a0.x, a0.y, a0.z, a0.w, a1.x, a1.y, a1.z, a1.w};
            float wv[4] = {w.x, w.y, w.z, w.w};
#pragma unroll
            for (int i = 0; i < 8; ++i)
#pragma unroll
                for (int j = 0; j < 4; ++j) acc2[i][j] += av[i] * wv[j];
        }
#pragma unroll
        for (int i = 0; i < 8; ++i) {
            int row = R0 + r0 + i;
            if (row < N_NODES) {
                float d = dinv[row];
                Half4 h;
                h.lo = __float22half2_rn(make_float2(d * acc2[i][0], d * acc2[i][1]));
                h.hi = __float22half2_rn(make_float2(d * acc2[i][2], d * acc2[i][3]));
                P[(long long)row * 16 + cg] = h;
            }
        }
    }
}

// ---------------- launch ----------------

extern "C" void kernel_launch(void* const* d_in, const int* in_sizes, int n_in,
                              void* d_out, int out_size, void* d_ws, size_t ws_size,
                              hipStream_t stream) {
    const float* x  = (const float*)d_in[0];
    const int*   ei = (const int*)d_in[1];
    const float* W1 = (const float*)d_in[2];
    const float* b1 = (const float*)d_in[3];
    const float* W2 = (const float*)d_in[4];
    const float* b2 = (const float*)d_in[5];
    float* out = (float*)d_out;

    const int* srcE = ei;            // edge_index[0]
    const int* dstE = ei + N_EDGES;  // edge_index[1]

    // workspace layout
    char* w = (char*)d_ws;
    int*   blockHist   = (int*)w;   w += sizeof(int) * NBLK_P * NBKT;
    int*   coarseStart = (int*)w;   w += sizeof(int) * (NBKT + 1);
    int*   rowstart    = (int*)w;   w += sizeof(int) * (N_NODES + 8);
    float* dinv        = (float*)w; w += sizeof(float) * (N_NODES + 8);
    int*   csr_src     = (int*)w;   w += sizeof(int) * N_EDGES;
    Half4* xs          = (Half4*)w; w += sizeof(Half4) * (size_t)N_NODES * 16;
    // union: sorted (E ints = 12.8MB) dies before agg1 (N*64 f32 = 25.6MB) is written
    int*   sorted      = (int*)w;
    float* agg1        = (float*)w; w += sizeof(float) * (size_t)N_NODES * 64;
    Half4* p2 = xs;  // xs dead after layer-1 gather; reuse for fp16 p2

    // CSR build (no global atomics) + fused dinv/scale
    k_coarse_hist<<<NBLK_P, 256, 0, stream>>>((const int4*)dstE, blockHist);
    k_colscan<<<1, 1024, 0, stream>>>(blockHist, coarseStart);
    k_partition<<<NBLK_P, 256, 0, stream>>>((const int4*)srcE, (const int4*)dstE,
                                            blockHist, sorted);
    k_fine<<<NBKT_USED, 256, 0, stream>>>(sorted, coarseStart, (const float4*)x,
                                          rowstart, dinv, csr_src, xs);

    // layer 1
    k_gather_h<<<(N_NODES + 3) / 4, 256, 0, stream>>>(rowstart, csr_src, dinv,
                                                      (const int4*)xs, nullptr,
                                                      (float4*)agg1);
    k_fused_gemm<<<(N_NODES + GTILE - 1) / GTILE, 256, 0, stream>>>(agg1, W1, b1, W2, dinv, p2);

    // layer 2: p2 already dinv-scaled fp16; gather into out (+b2)
    k_gather_h<<<(N_NODES + 3) / 4, 256, 0, stream>>>(rowstart, csr_src, dinv,
                                                      (const int4*)p2, (const float4*)b2,
                                                      (float4*)out);
}